// Round 3
// baseline (175.219 us; speedup 1.0000x reference)
//
#include <hip/hip_runtime.h>

// FilteredNoiseGenerator: B=32, t=4000, nbands=65, framesize=80, L_fir=129, L=208
// out[b,p] = sum_{f,m} x[b,f,m]*w[b,f,tau], tau = (p+64) - 80f - m in [0,128]
// P1 (firwin) = GEMM vs fixed matrix M (MFMA f16, M in d_ws, frag-order).
// R11: block-granularity attack (R10 confirmed latency-bound + occupancy-coupled:
//     6->7 blocks/CU gave -13%). Halve block: 16 frames, NT=128 (col=t&15,
//     pb=t>>4 -> P2 per-thread shape bit-identical to R10). LDS 21,720 ->
//     11,848 B => 13 blocks/CU (26 waves, 81% cap). Grid 250x32=8000 blocks.
//     Per-CU independent blocks 7->13: P0/P1 latency + barriers of one block
//     hide under P2 of others. Cost: halo staging 9%->19% (+5% fetch), P1
//     MFMA/frame +33% (MfmaUtil 2.7% -- irrelevant).

#define NT 128
#define FPB 16             // output frames per block
#define NSLOT 19           // frames f0-2 .. f0+16
#define X_STRIDE 84        // f16 x row stride; 168 B rows (8B-aligned), 42 dw -> 2-way banks (free)
#define W_STRIDE 154       // f16 w row; 77 dw/row, gcd(77,32)=1 -> conflict-free
#define W_P 24             // w[tau] at wr[W_P+tau]; tau in [0,128]; zeros outside
#define WTOT_H 2952        // >= 18*154 + 176 (max windowed read spills into pads); /8 int
#define HF_STRIDE 72       // f16 H row stride (144 B, 16B-aligned b128 frag loads)
#define ZSTUB 1368         // 19*72; 16B-aligned zero stub for k>=72 A-frags
#define HTOT_H 1376        // 19*72 + 8
#define XTOT_H 1596        // 19*84

typedef _Float16 f16x8 __attribute__((ext_vector_type(8)));
typedef _Float16 f16x4 __attribute__((ext_vector_type(4)));
typedef _Float16 h2 __attribute__((ext_vector_type(2)));
typedef float f32x4 __attribute__((ext_vector_type(4)));

union U32H2 { unsigned u; h2 h; };
static __device__ __forceinline__ h2 mid_h2(h2 lo, h2 hi) {    // (lo.y, hi.x)
  U32H2 a, b; a.h = lo; b.h = hi;
  U32H2 o; o.u = __builtin_amdgcn_alignbit(b.u, a.u, 16);
  return o.h;
}

// ---- init: M in MFMA B-operand frag order (R6-proven). frag (nt,ks) of 27;
// lane holds B[k = ks*32 + (lane>>4)*8 + j][n = nt*16 + (lane&15)], j=0..7.
__global__ void __launch_bounds__(256)
minit_kernel(_Float16* __restrict__ M) {
  const float TP = 6.28318530717958647692f / 129.f;
  int i = blockIdx.x * 256 + threadIdx.x;      // 54*256 = 13824 = 27*512 exactly
  int frag = i >> 9;
  int off  = i & 511;
  int lane = off >> 3, j = off & 7;
  int nt = frag / 3, ks = frag - 3 * (frag / 3);
  int n = nt * 16 + (lane & 15);
  int k = ks * 32 + (lane >> 4) * 8 + j;
  float v = 0.f;
  if (n <= 128 && k <= 64) {
    float hann = 0.5f - 0.5f * __cosf((float)n * TP);
    float sc = (k == 0 ? 1.f : 2.f) * (1.f / 129.f);
    int e = (k * (n - 64)) % 129; if (e < 0) e += 129;   // exact arg reduction
    v = hann * sc * __cosf((float)e * TP);
  }
  M[i] = (_Float16)v;
}

__global__ void __launch_bounds__(NT, 7)
fng_kernel(const float* __restrict__ Hg_, const float* __restrict__ Ng_,
           float* __restrict__ Og_, const _Float16* __restrict__ Mg) {
  __shared__ __align__(16) _Float16 sWh[WTOT_H];   // 5,904 B firwin f16, zero-padded
  __shared__ __align__(16) _Float16 sXh[XTOT_H];   // 3,192 B x f16, REVERSED rows
  __shared__ __align__(16) _Float16 sHf[HTOT_H];   // 2,752 B H f16 (P1 A-operand)

  const int t  = threadIdx.x;
  const int bx = blockIdx.x;     // 0..249 (16 output-frames each)
  const int b  = blockIdx.y;     // 0..31
  const int f0 = bx * FPB;

  // ---------------- P0a: zero sWh (data overwritten by P1; pads stay 0) ----
  {
    float4 z4 = {0.f, 0.f, 0.f, 0.f};
    for (int i = t; i < WTOT_H / 8; i += NT) ((float4*)sWh)[i] = z4;
    if (t == 0) *(float4*)&sHf[ZSTUB] = z4;        // 16B zero stub (k>=72 A-frags)
  }

  // ---------------- P0b: H -> f16 LDS, 4-elem units (19 rows x 18 units) ----
  // u<16: data quad (cols 4u..4u+3 <= 63); u==16: col 64 + zeros 65..67;
  // u==17: zeros 68..71.
  {
    const float* Hg = Hg_ + (size_t)b * (4000 * 65);
#pragma unroll
    for (int j = 0; j < 3; ++j) {
      int i = t + NT * j;
      if (i < NSLOT * 18) {
        int r = i / 18, u = i - 18 * r;
        int fr = f0 - 2 + r;
        f16x4 o = {(_Float16)0.f, (_Float16)0.f, (_Float16)0.f, (_Float16)0.f};
        if (u < 16) {
          if (fr >= 0 && fr < 4000) {
            const float* hp = &Hg[fr * 65 + 4 * u];
            o.x = (_Float16)hp[0]; o.y = (_Float16)hp[1];
            o.z = (_Float16)hp[2]; o.w = (_Float16)hp[3];
          }
          *(f16x4*)&sHf[r * HF_STRIDE + 4 * u] = o;
        } else if (u == 16) {
          if (fr >= 0 && fr < 4000) o.x = (_Float16)Hg[fr * 65 + 64];
          *(f16x4*)&sHf[r * HF_STRIDE + 64] = o;     // k=64 + zeros 65..67
        } else {
          *(f16x4*)&sHf[r * HF_STRIDE + 68] = o;     // zeros k=68..71
        }
      }
    }
  }

  // ---------------- P0c: noise -> sXh REVERSED f16 (xr[u] = 2*noise[79-u]-1) --
  {
    const float* Ng = Ng_ + (size_t)b * 320000;
#pragma unroll
    for (int j = 0; j < 3; ++j) {
      int q = t + NT * j;
      if (q < NSLOT * 20) {
        int fi = q / 20, qm = q - 20 * fi;
        int fr = f0 - 2 + fi;
        f16x4 o = {(_Float16)0.f, (_Float16)0.f, (_Float16)0.f, (_Float16)0.f};
        if (fr >= 0 && fr < 4000) {
          float4 v = *(const float4*)&Ng[(size_t)fr * 80 + 4 * qm];
          o.x = (_Float16)(2.f * v.w - 1.f);   // x[4qm+3]
          o.y = (_Float16)(2.f * v.z - 1.f);   // x[4qm+2]
          o.z = (_Float16)(2.f * v.y - 1.f);   // x[4qm+1]
          o.w = (_Float16)(2.f * v.x - 1.f);   // x[4qm]
        }
        *(f16x4*)&sXh[fi * X_STRIDE + (76 - 4 * qm)] = o;   // 8B-aligned
      }
    }
  }
  __syncthreads();

  // ------- P1: firwin = H x M^T via MFMA 16x16x32 f16 (R6-proven layout) -------
  // 18 tiles (2 mt x 9 nt) over 2 waves. A rows clamped to 18: rows>=19 produce
  // only discarded C rows (frame>=NSLOT). ks==2/quad>0 A-frags (k 72..95) read
  // the zero stub: M rows k>=65 are zero, so products vanish; stub avoids NaNs.
  {
    const int wv   = t >> 6;
    const int lane = t & 63;
    const int quad = lane >> 4;
    const int l15  = lane & 15;
#pragma unroll 1
    for (int tile = wv; tile < 18; tile += 2) {
      const int mt = tile / 9, nt = tile - 9 * (tile / 9);
      const int rr = mt * 16 + l15;
      const int row = (rr > 18) ? 18 : rr;
      f32x4 acc = {0.f, 0.f, 0.f, 0.f};
#pragma unroll
      for (int ks = 0; ks < 3; ++ks) {
        const _Float16* ap;
        if (ks == 2) ap = (quad > 0) ? &sHf[ZSTUB] : &sHf[row * HF_STRIDE + 64];
        else         ap = &sHf[row * HF_STRIDE + ks * 32 + quad * 8];
        f16x8 a = *(const f16x8*)ap;
        f16x8 bb = ((const f16x8*)Mg)[(nt * 3 + ks) * 64 + lane];
        acc = __builtin_amdgcn_mfma_f32_16x16x32_f16(a, bb, acc, 0, 0, 0);
      }
      const int n = nt * 16 + l15;
      const int fr0 = mt * 16 + quad * 4;
      if (n <= 128) {
#pragma unroll
        for (int r = 0; r < 4; ++r) {
          int frame = fr0 + r;
          if (frame < NSLOT) sWh[frame * W_STRIDE + W_P + n] = (_Float16)acc[r];
        }
      }
    }
  }
  __syncthreads();

  // ------- P2: gather convolution, 8-m-wide trips, reversed-x (no swaps) -------
  // Per-thread shape IDENTICAL to R10 (10 outputs, same D set, same trips,
  // same summation order -> bit-identical results).
  {
    const int col = t & 15;
    const int pb  = t >> 4;
    const int e   = 64 + 10 * pb;
    const int qq  = (e >= 80) ? 1 : 0;
    const int D   = e - 80 * qq;                    // per thread uniform, even
    float acc[10];
#pragma unroll
    for (int i = 0; i < 10; ++i) acc[i] = 0.f;

#pragma unroll 1
    for (int g = 2; g >= -1; --g) {                 // source frame F - g
      const int dlt = D + 80 * g;                   // even
      int Ulo = (dlt - 128) >> 3; if (Ulo < 0) Ulo = 0;
      int Uhi = (dlt + 9) >> 3;   if (Uhi > 9) Uhi = 9;
      if (Ulo > Uhi) continue;
      const int slot = col + qq - g + 2;            // 0..18
      const _Float16* wr = &sWh[slot * W_STRIDE];
      const _Float16* xr = &sXh[slot * X_STRIDE];
      int wb = W_P + dlt - 8 * Ulo - 4;             // even; running tap base

      // w-window: wEa[k] = (w[wb-4+2k], w[wb-4+2k+1]) even-aligned b32 loads,
      // wOa[k] = odd pair via alignbit. PAIR(K)=(wr[wb+K], wr[wb+K+1]),
      // K in [-3,13] used. All out-of-range taps land in zero pads.
      h2 wEa[10], wOa[9];
#pragma unroll
      for (int k2 = 0; k2 < 10; ++k2) wEa[k2] = *(const h2*)&wr[wb - 4 + 2 * k2];
#pragma unroll
      for (int k2 = 0; k2 < 9; ++k2) wOa[k2] = mid_h2(wEa[k2], wEa[k2 + 1]);

#define PAIRX(K) (((K) & 1) ? wOa[(((K) - 1) >> 1) + 2] : wEa[(((K) >> 1) + 2)])
#pragma unroll 4
      for (int U = Ulo; U <= Uhi; ++U) {
        // reversed rows: xr[u]=x[79-u] -> aligned b64s give descending pairs free
        const _Float16* xp = &xr[72 - 8 * U];
        f16x4 q0 = *(const f16x4*)&xp[0];           // (x7,x6,x5,x4) of m=8U+..
        f16x4 q1 = *(const f16x4*)&xp[4];           // (x3,x2,x1,x0)
        h2 xD; xD.x = q0.x; xD.y = q0.y;            // (x7,x6) — reg halves, free
        h2 xC; xC.x = q0.z; xC.y = q0.w;            // (x5,x4)
        h2 xB; xB.x = q1.x; xB.y = q1.y;            // (x3,x2)
        h2 xA; xA.x = q1.z; xA.y = q1.w;            // (x1,x0)
#pragma unroll
        for (int i = 0; i < 10; ++i) {
          float a = acc[i];
          a = __builtin_amdgcn_fdot2(xA, PAIRX(i + 3), a, false);  // m 8U+0,1
          a = __builtin_amdgcn_fdot2(xB, PAIRX(i + 1), a, false);  // m 8U+2,3
          a = __builtin_amdgcn_fdot2(xC, PAIRX(i - 1), a, false);  // m 8U+4,5
          a = __builtin_amdgcn_fdot2(xD, PAIRX(i - 3), a, false);  // m 8U+6,7
          acc[i] = a;
        }
        // slide window down 8 f16 = 4 pair-slots; W_P=24 => wb-12 >= 0 always
        const _Float16* wp = &wr[wb - 12];
#pragma unroll
        for (int k2 = 9; k2 >= 4; --k2) wEa[k2] = wEa[k2 - 4];
#pragma unroll
        for (int k2 = 8; k2 >= 4; --k2) wOa[k2] = wOa[k2 - 4];
        wEa[0] = *(const h2*)&wp[0];
        wEa[1] = *(const h2*)&wp[2];
        wEa[2] = *(const h2*)&wp[4];
        wEa[3] = *(const h2*)&wp[6];
        wOa[0] = mid_h2(wEa[0], wEa[1]);
        wOa[1] = mid_h2(wEa[1], wEa[2]);
        wOa[2] = mid_h2(wEa[2], wEa[3]);
        wOa[3] = mid_h2(wEa[3], wEa[4]);
        wb -= 8;
      }
#undef PAIRX
    }

    // exactly-once writeout: u0 = 80*col + 10*pb (even -> float2 stores)
    float* Ob = Og_ + (size_t)b * 320000 + 1280 * bx + 80 * col + 10 * pb;
#pragma unroll
    for (int s = 0; s < 5; ++s) {
      float2 v; v.x = acc[2 * s]; v.y = acc[2 * s + 1];
      *(float2*)&Ob[2 * s] = v;
    }
  }
}

extern "C" void kernel_launch(void* const* d_in, const int* in_sizes, int n_in,
                              void* d_out, int out_size, void* d_ws, size_t ws_size,
                              hipStream_t stream) {
  const float* H     = (const float*)d_in[0];   // [32,4000,65] fp32
  const float* noise = (const float*)d_in[1];   // [32,4000,80] fp32
  float* out = (float*)d_out;                   // [32,320000] fp32
  _Float16* M = (_Float16*)d_ws;                // 27,648 B of scratch
  (void)in_sizes; (void)n_in; (void)ws_size; (void)out_size;

  minit_kernel<<<54, 256, 0, stream>>>(M);      // rebuilt every call (ws re-poisoned)
  dim3 grid(250, 32, 1);
  fng_kernel<<<grid, NT, 0, stream>>>(H, noise, out, M);
}

// Round 4
// 153.771 us; speedup vs baseline: 1.1395x; 1.1395x over previous
//
#include <hip/hip_runtime.h>

// FilteredNoiseGenerator: B=32, t=4000, nbands=65, framesize=80, L_fir=129, L=208
// out[b,p] = sum_{f,m} x[b,f,m]*w[b,f,tau], tau = (p+64) - 80f - m in [0,128]
// P1 (firwin) = GEMM vs fixed matrix M (MFMA f16, M in d_ws, frag-order).
// R12: back to NT=256/FPB=32 (R11's NT=128 regressed: occupancy didn't rise,
//     bank conflicts 4.6x from 4 pb-phases/wave). Occupancy attack instead:
//     - sHf + P0b deleted: P1 A-frags load 8 consecutive f32 of an H row per
//       lane DIRECT from global (clamped addr, zero-selected value, scalar
//       col-64 tail), cvt f32->f16 in regs (bit-identical). Wave wv<3 owns
//       mt=wv (16 rows x 9 nt tiles).
//     - barrier #1 deleted: P0a zeroes ONLY sWh pad cells ([0,24) + per-row
//       [153,178) chunks), disjoint from P1's data writes [24,153) -> no race.
//     - LDS 21,720 -> 16,712 B (alloc 16,896) => 8 blocks/CU = 32/32 waves.
//     P2 verbatim R10 -> bit-identical output.

#define NT 256
#define X_STRIDE 84        // f16 x row stride; 168 B rows (8B-aligned), 42 dw -> 2-way banks (free)
#define W_STRIDE 154       // f16 w row; 77 dw/row, gcd(77,32)=1 -> conflict-free
#define W_P 24             // w[tau] at wr[W_P+tau]; tau in [0,128]; zeros outside
#define NSLOT 35           // frames f0-2 .. f0+32
#define WTOT_H 5416        // 34*154 + 178 = 5414 max pad write; 16B-aligned total
#define XTOT_H 2940        // 35*84

typedef _Float16 f16x8 __attribute__((ext_vector_type(8)));
typedef _Float16 f16x4 __attribute__((ext_vector_type(4)));
typedef _Float16 h2 __attribute__((ext_vector_type(2)));
typedef float f32x4 __attribute__((ext_vector_type(4)));

union U32H2 { unsigned u; h2 h; };
static __device__ __forceinline__ h2 mid_h2(h2 lo, h2 hi) {    // (lo.y, hi.x)
  U32H2 a, b; a.h = lo; b.h = hi;
  U32H2 o; o.u = __builtin_amdgcn_alignbit(b.u, a.u, 16);
  return o.h;
}

// ---- init: M in MFMA B-operand frag order (R6-proven). frag (nt,ks) of 27;
// lane holds B[k = ks*32 + (lane>>4)*8 + j][n = nt*16 + (lane&15)], j=0..7.
__global__ void __launch_bounds__(256)
minit_kernel(_Float16* __restrict__ M) {
  const float TP = 6.28318530717958647692f / 129.f;
  int i = blockIdx.x * 256 + threadIdx.x;      // 54*256 = 13824 = 27*512 exactly
  int frag = i >> 9;
  int off  = i & 511;
  int lane = off >> 3, j = off & 7;
  int nt = frag / 3, ks = frag - 3 * (frag / 3);
  int n = nt * 16 + (lane & 15);
  int k = ks * 32 + (lane >> 4) * 8 + j;
  float v = 0.f;
  if (n <= 128 && k <= 64) {
    float hann = 0.5f - 0.5f * __cosf((float)n * TP);
    float sc = (k == 0 ? 1.f : 2.f) * (1.f / 129.f);
    int e = (k * (n - 64)) % 129; if (e < 0) e += 129;   // exact arg reduction
    v = hann * sc * __cosf((float)e * TP);
  }
  M[i] = (_Float16)v;
}

__global__ void __launch_bounds__(NT, 8)
fng_kernel(const float* __restrict__ Hg_, const float* __restrict__ Ng_,
           float* __restrict__ Og_, const _Float16* __restrict__ Mg) {
  __shared__ __align__(16) _Float16 sWh[WTOT_H];   // 10,832 B firwin f16
  __shared__ __align__(16) _Float16 sXh[XTOT_H];   //  5,880 B x f16, REVERSED rows

  const int t  = threadIdx.x;
  const int bx = blockIdx.x;     // 0..124 (32 output-frames each)
  const int b  = blockIdx.y;     // 0..31
  const int f0 = bx * 32;

  // ---- P0a: zero ONLY the pad cells of sWh (disjoint from P1 data writes).
  // Pads: [0,24) front of row 0; for c in 0..34 the 25-cell run
  // [c*154+153, c*154+178) = back pad of row c + front pad of row c+1
  // (c==34's run is the overreach tail). 24 + 35*25 = 899 cells.
  {
#pragma unroll
    for (int it = 0; it < 4; ++it) {
      int j = t + NT * it;
      if (j < 24) {
        sWh[j] = (_Float16)0.f;
      } else if (j < 899) {
        int jj = j - 24;
        int c = jj / 25, o = jj - 25 * c;
        sWh[c * W_STRIDE + 153 + o] = (_Float16)0.f;
      }
    }
  }

  // ---- P0c: noise -> sXh REVERSED f16 (xr[u] = 2*noise[79-u]-1) ----
  {
    const float* Ng = Ng_ + (size_t)b * 320000;
#pragma unroll
    for (int j = 0; j < 3; ++j) {
      int q = t + NT * j;
      if (q < NSLOT * 20) {
        int fi = q / 20, qm = q - 20 * fi;
        int fr = f0 - 2 + fi;
        f16x4 o = {(_Float16)0.f, (_Float16)0.f, (_Float16)0.f, (_Float16)0.f};
        if (fr >= 0 && fr < 4000) {
          float4 v = *(const float4*)&Ng[(size_t)fr * 80 + 4 * qm];
          o.x = (_Float16)(2.f * v.w - 1.f);   // x[4qm+3]
          o.y = (_Float16)(2.f * v.z - 1.f);   // x[4qm+2]
          o.z = (_Float16)(2.f * v.y - 1.f);   // x[4qm+1]
          o.w = (_Float16)(2.f * v.x - 1.f);   // x[4qm]
        }
        *(f16x4*)&sXh[fi * X_STRIDE + (76 - 4 * qm)] = o;   // 8B-aligned
      }
    }
  }

  // ---- P1: firwin = H x M^T via MFMA 16x16x32 f16; A direct from global ----
  // Wave wv (0..2) owns mt=wv: A rows f0-2+mt*16+l15, cols [0,64] as f32 ->
  // f16 regs (same convert the LDS path did -> bit-identical). Rows outside
  // [0,4000) -> zero A-frag. k in [65,96): M rows are zero -> A value is
  // irrelevant; we supply zeros. C rows (frames) >= NSLOT discarded by guard.
  {
    const int wv   = t >> 6;
    const int lane = t & 63;
    if (wv < 3) {
      const int quad = lane >> 4;
      const int l15  = lane & 15;
      const int mt   = wv;
      const int fr   = f0 - 2 + mt * 16 + l15;
      const bool va  = (fr >= 0 && fr < 4000);
      const int frc  = va ? fr : 0;                 // clamped addr, always valid
      const float* hr = Hg_ + (size_t)b * 260000 + (size_t)frc * 65;

      float c0[8], c1[8];                           // cols quad*8.. / 32+quad*8..
      __builtin_memcpy(c0, &hr[quad * 8], 32);      // 4B-aligned safe
      __builtin_memcpy(c1, &hr[32 + quad * 8], 32);
      float s64 = hr[64];
      if (!va) {
#pragma unroll
        for (int j = 0; j < 8; ++j) { c0[j] = 0.f; c1[j] = 0.f; }
        s64 = 0.f;
      }
      f16x8 a0, a1, a2;
#pragma unroll
      for (int j = 0; j < 8; ++j) {
        a0[j] = (_Float16)c0[j];
        a1[j] = (_Float16)c1[j];
        a2[j] = (_Float16)0.f;
      }
      if (quad == 0) a2[0] = (_Float16)s64;         // col 64; cols 65..71 zero

#pragma unroll 3
      for (int nt = 0; nt < 9; ++nt) {
        f32x4 acc = {0.f, 0.f, 0.f, 0.f};
        f16x8 b0 = ((const f16x8*)Mg)[(nt * 3 + 0) * 64 + lane];
        f16x8 b1 = ((const f16x8*)Mg)[(nt * 3 + 1) * 64 + lane];
        f16x8 b2 = ((const f16x8*)Mg)[(nt * 3 + 2) * 64 + lane];
        acc = __builtin_amdgcn_mfma_f32_16x16x32_f16(a0, b0, acc, 0, 0, 0);
        acc = __builtin_amdgcn_mfma_f32_16x16x32_f16(a1, b1, acc, 0, 0, 0);
        acc = __builtin_amdgcn_mfma_f32_16x16x32_f16(a2, b2, acc, 0, 0, 0);
        const int n = nt * 16 + l15;
        if (n <= 128) {
          const int fb = mt * 16 + quad * 4;
#pragma unroll
          for (int r = 0; r < 4; ++r) {
            int frame = fb + r;
            if (frame < NSLOT) sWh[frame * W_STRIDE + W_P + n] = (_Float16)acc[r];
          }
        }
      }
    }
  }
  __syncthreads();   // single barrier: pads + x + w all visible

  // ------- P2: gather convolution, 8-m-wide trips, reversed-x (no swaps) -------
  // Verbatim R10 (same per-thread shape, same summation order -> bit-identical).
  {
    const int col = t & 31;
    const int pb  = t >> 5;
    const int e   = 64 + 10 * pb;
    const int qq  = (e >= 80) ? 1 : 0;
    const int D   = e - 80 * qq;                    // per half-wave uniform, even
    float acc[10];
#pragma unroll
    for (int i = 0; i < 10; ++i) acc[i] = 0.f;

#pragma unroll 1
    for (int g = 2; g >= -1; --g) {                 // source frame F - g
      const int dlt = D + 80 * g;                   // even
      int Ulo = (dlt - 128) >> 3; if (Ulo < 0) Ulo = 0;
      int Uhi = (dlt + 9) >> 3;   if (Uhi > 9) Uhi = 9;
      if (Ulo > Uhi) continue;
      const int slot = col + qq - g + 2;            // 0..34
      const _Float16* wr = &sWh[slot * W_STRIDE];
      const _Float16* xr = &sXh[slot * X_STRIDE];
      int wb = W_P + dlt - 8 * Ulo - 4;             // even; running tap base

      // w-window: wEa[k] = (w[wb-4+2k], w[wb-4+2k+1]) even-aligned b32 loads,
      // wOa[k] = odd pair via alignbit. PAIR(K)=(wr[wb+K], wr[wb+K+1]),
      // K in [-3,13] used. All out-of-range taps land in zero pads.
      h2 wEa[10], wOa[9];
#pragma unroll
      for (int k2 = 0; k2 < 10; ++k2) wEa[k2] = *(const h2*)&wr[wb - 4 + 2 * k2];
#pragma unroll
      for (int k2 = 0; k2 < 9; ++k2) wOa[k2] = mid_h2(wEa[k2], wEa[k2 + 1]);

#define PAIRX(K) (((K) & 1) ? wOa[(((K) - 1) >> 1) + 2] : wEa[(((K) >> 1) + 2)])
#pragma unroll 4
      for (int U = Ulo; U <= Uhi; ++U) {
        // reversed rows: xr[u]=x[79-u] -> aligned b64s give descending pairs free
        const _Float16* xp = &xr[72 - 8 * U];
        f16x4 q0 = *(const f16x4*)&xp[0];           // (x7,x6,x5,x4) of m=8U+..
        f16x4 q1 = *(const f16x4*)&xp[4];           // (x3,x2,x1,x0)
        h2 xD; xD.x = q0.x; xD.y = q0.y;            // (x7,x6) — reg halves, free
        h2 xC; xC.x = q0.z; xC.y = q0.w;            // (x5,x4)
        h2 xB; xB.x = q1.x; xB.y = q1.y;            // (x3,x2)
        h2 xA; xA.x = q1.z; xA.y = q1.w;            // (x1,x0)
#pragma unroll
        for (int i = 0; i < 10; ++i) {
          float a = acc[i];
          a = __builtin_amdgcn_fdot2(xA, PAIRX(i + 3), a, false);  // m 8U+0,1
          a = __builtin_amdgcn_fdot2(xB, PAIRX(i + 1), a, false);  // m 8U+2,3
          a = __builtin_amdgcn_fdot2(xC, PAIRX(i - 1), a, false);  // m 8U+4,5
          a = __builtin_amdgcn_fdot2(xD, PAIRX(i - 3), a, false);  // m 8U+6,7
          acc[i] = a;
        }
        // slide window down 8 f16 = 4 pair-slots; W_P=24 => wb-12 >= 0 always
        const _Float16* wp = &wr[wb - 12];
#pragma unroll
        for (int k2 = 9; k2 >= 4; --k2) wEa[k2] = wEa[k2 - 4];
#pragma unroll
        for (int k2 = 8; k2 >= 4; --k2) wOa[k2] = wOa[k2 - 4];
        wEa[0] = *(const h2*)&wp[0];
        wEa[1] = *(const h2*)&wp[2];
        wEa[2] = *(const h2*)&wp[4];
        wEa[3] = *(const h2*)&wp[6];
        wOa[0] = mid_h2(wEa[0], wEa[1]);
        wOa[1] = mid_h2(wEa[1], wEa[2]);
        wOa[2] = mid_h2(wEa[2], wEa[3]);
        wOa[3] = mid_h2(wEa[3], wEa[4]);
        wb -= 8;
      }
#undef PAIRX
    }

    // exactly-once writeout: u0 = 80*col + 10*pb (even -> float2 stores)
    float* Ob = Og_ + (size_t)b * 320000 + 2560 * bx + 80 * col + 10 * pb;
#pragma unroll
    for (int s = 0; s < 5; ++s) {
      float2 v; v.x = acc[2 * s]; v.y = acc[2 * s + 1];
      *(float2*)&Ob[2 * s] = v;
    }
  }
}

extern "C" void kernel_launch(void* const* d_in, const int* in_sizes, int n_in,
                              void* d_out, int out_size, void* d_ws, size_t ws_size,
                              hipStream_t stream) {
  const float* H     = (const float*)d_in[0];   // [32,4000,65] fp32
  const float* noise = (const float*)d_in[1];   // [32,4000,80] fp32
  float* out = (float*)d_out;                   // [32,320000] fp32
  _Float16* M = (_Float16*)d_ws;                // 27,648 B of scratch
  (void)in_sizes; (void)n_in; (void)ws_size; (void)out_size;

  minit_kernel<<<54, 256, 0, stream>>>(M);      // rebuilt every call (ws re-poisoned)
  dim3 grid(125, 32, 1);
  fng_kernel<<<grid, NT, 0, stream>>>(H, noise, out, M);
}

// Round 5
// 151.511 us; speedup vs baseline: 1.1565x; 1.0149x over previous
//
#include <hip/hip_runtime.h>

// FilteredNoiseGenerator: B=32, t=4000, nbands=65, framesize=80, L_fir=129, L=208
// out[b,p] = sum_{f,m} x[b,f,m]*w[b,f,tau], tau = (p+64) - 80f - m in [0,128]
// P1 (firwin) = GEMM vs fixed matrix M (MFMA f16, M in d_ws, frag-order).
// R13: load-scheduling attack (R12: occ 71%, VALU 52%, dur -6% -- wave-slots
//     maxed, residual is correlated stalls). Arithmetic bit-identical to R12:
//     - H global loads issued at kernel TOP (waves 0-2), raw f32 kept in regs
//       through P0c (noise staging runs under H-load latency), converted at P1.
//     - P2 U-loop x reads get an explicit 1-trip prefetch (q=p; p=load(next));
//       8-f16 front pad on sXh keeps the final (dead) prefetch in-bounds.
//       w-slide already had 1-trip distance; now both operand streams do.

#define NT 256
#define X_STRIDE 84        // f16 x row stride; 168 B rows (8B-aligned), 42 dw -> 2-way banks (free)
#define XPAD 8             // front pad so U-loop prefetch (down to xr[-8]) is in-bounds
#define W_STRIDE 154       // f16 w row; 77 dw/row, gcd(77,32)=1 -> conflict-free
#define W_P 24             // w[tau] at wr[W_P+tau]; tau in [0,128]; zeros outside
#define NSLOT 35           // frames f0-2 .. f0+32
#define WTOT_H 5416        // 34*154 + 178 = 5414 max pad write; 16B-aligned total
#define XTOT_H 2948        // XPAD + 35*84

typedef _Float16 f16x8 __attribute__((ext_vector_type(8)));
typedef _Float16 f16x4 __attribute__((ext_vector_type(4)));
typedef _Float16 h2 __attribute__((ext_vector_type(2)));
typedef float f32x4 __attribute__((ext_vector_type(4)));

union U32H2 { unsigned u; h2 h; };
static __device__ __forceinline__ h2 mid_h2(h2 lo, h2 hi) {    // (lo.y, hi.x)
  U32H2 a, b; a.h = lo; b.h = hi;
  U32H2 o; o.u = __builtin_amdgcn_alignbit(b.u, a.u, 16);
  return o.h;
}

// ---- init: M in MFMA B-operand frag order (R6-proven). frag (nt,ks) of 27;
// lane holds B[k = ks*32 + (lane>>4)*8 + j][n = nt*16 + (lane&15)], j=0..7.
__global__ void __launch_bounds__(256)
minit_kernel(_Float16* __restrict__ M) {
  const float TP = 6.28318530717958647692f / 129.f;
  int i = blockIdx.x * 256 + threadIdx.x;      // 54*256 = 13824 = 27*512 exactly
  int frag = i >> 9;
  int off  = i & 511;
  int lane = off >> 3, j = off & 7;
  int nt = frag / 3, ks = frag - 3 * (frag / 3);
  int n = nt * 16 + (lane & 15);
  int k = ks * 32 + (lane >> 4) * 8 + j;
  float v = 0.f;
  if (n <= 128 && k <= 64) {
    float hann = 0.5f - 0.5f * __cosf((float)n * TP);
    float sc = (k == 0 ? 1.f : 2.f) * (1.f / 129.f);
    int e = (k * (n - 64)) % 129; if (e < 0) e += 129;   // exact arg reduction
    v = hann * sc * __cosf((float)e * TP);
  }
  M[i] = (_Float16)v;
}

__global__ void __launch_bounds__(NT, 8)
fng_kernel(const float* __restrict__ Hg_, const float* __restrict__ Ng_,
           float* __restrict__ Og_, const _Float16* __restrict__ Mg) {
  __shared__ __align__(16) _Float16 sWh[WTOT_H];   // 10,832 B firwin f16
  __shared__ __align__(16) _Float16 sXh[XTOT_H];   //  5,896 B x f16, REVERSED rows

  const int t  = threadIdx.x;
  const int bx = blockIdx.x;     // 0..124 (32 output-frames each)
  const int b  = blockIdx.y;     // 0..31
  const int f0 = bx * 32;

  const int wv   = t >> 6;
  const int lane = t & 63;

  // ---- issue H loads FIRST (waves 0-2): raw f32 in regs; the wait lands at
  // P1's converts, after P0a/P0c have executed under the load latency.
  float c0[8], c1[8];
  float s64 = 0.f;
  bool  va  = false;
  {
    if (wv < 3) {
      const int quad = lane >> 4;
      const int l15  = lane & 15;
      const int fr   = f0 - 2 + wv * 16 + l15;
      va = (fr >= 0 && fr < 4000);
      const int frc  = va ? fr : 0;               // clamped addr, always valid
      const float* hr = Hg_ + (size_t)b * 260000 + (size_t)frc * 65;
      __builtin_memcpy(c0, &hr[quad * 8], 32);    // 4B-aligned safe
      __builtin_memcpy(c1, &hr[32 + quad * 8], 32);
      s64 = hr[64];
    }
  }

  // ---- P0a: zero ONLY the pad cells of sWh (disjoint from P1 data writes).
  // Pads: [0,24) front of row 0; for c in 0..34 the 25-cell run
  // [c*154+153, c*154+178). 24 + 35*25 = 899 cells.
  {
#pragma unroll
    for (int it = 0; it < 4; ++it) {
      int j = t + NT * it;
      if (j < 24) {
        sWh[j] = (_Float16)0.f;
      } else if (j < 899) {
        int jj = j - 24;
        int c = jj / 25, o = jj - 25 * c;
        sWh[c * W_STRIDE + 153 + o] = (_Float16)0.f;
      }
    }
  }

  // ---- P0c: noise -> sXh REVERSED f16 (xr[u] = 2*noise[79-u]-1) ----
  {
    const float* Ng = Ng_ + (size_t)b * 320000;
#pragma unroll
    for (int j = 0; j < 3; ++j) {
      int q = t + NT * j;
      if (q < NSLOT * 20) {
        int fi = q / 20, qm = q - 20 * fi;
        int fr = f0 - 2 + fi;
        f16x4 o = {(_Float16)0.f, (_Float16)0.f, (_Float16)0.f, (_Float16)0.f};
        if (fr >= 0 && fr < 4000) {
          float4 v = *(const float4*)&Ng[(size_t)fr * 80 + 4 * qm];
          o.x = (_Float16)(2.f * v.w - 1.f);   // x[4qm+3]
          o.y = (_Float16)(2.f * v.z - 1.f);   // x[4qm+2]
          o.z = (_Float16)(2.f * v.y - 1.f);   // x[4qm+1]
          o.w = (_Float16)(2.f * v.x - 1.f);   // x[4qm]
        }
        *(f16x4*)&sXh[XPAD + fi * X_STRIDE + (76 - 4 * qm)] = o;   // 8B-aligned
      }
    }
  }

  // ---- P1: firwin = H x M^T via MFMA 16x16x32 f16; A from the early loads ----
  // Rows outside [0,4000) -> zero A-frag. k in [65,96): M rows are zero ->
  // zeros supplied. C rows (frames) >= NSLOT discarded by guard.
  {
    if (wv < 3) {
      const int quad = lane >> 4;
      const int l15  = lane & 15;
      const int mt   = wv;
      if (!va) {
#pragma unroll
        for (int j = 0; j < 8; ++j) { c0[j] = 0.f; c1[j] = 0.f; }
        s64 = 0.f;
      }
      f16x8 a0, a1, a2;
#pragma unroll
      for (int j = 0; j < 8; ++j) {
        a0[j] = (_Float16)c0[j];
        a1[j] = (_Float16)c1[j];
        a2[j] = (_Float16)0.f;
      }
      if (quad == 0) a2[0] = (_Float16)s64;       // col 64; cols 65..71 zero

#pragma unroll 3
      for (int nt = 0; nt < 9; ++nt) {
        f32x4 acc = {0.f, 0.f, 0.f, 0.f};
        f16x8 b0 = ((const f16x8*)Mg)[(nt * 3 + 0) * 64 + lane];
        f16x8 b1 = ((const f16x8*)Mg)[(nt * 3 + 1) * 64 + lane];
        f16x8 b2 = ((const f16x8*)Mg)[(nt * 3 + 2) * 64 + lane];
        acc = __builtin_amdgcn_mfma_f32_16x16x32_f16(a0, b0, acc, 0, 0, 0);
        acc = __builtin_amdgcn_mfma_f32_16x16x32_f16(a1, b1, acc, 0, 0, 0);
        acc = __builtin_amdgcn_mfma_f32_16x16x32_f16(a2, b2, acc, 0, 0, 0);
        const int n = nt * 16 + l15;
        if (n <= 128) {
          const int fb = mt * 16 + quad * 4;
#pragma unroll
          for (int r = 0; r < 4; ++r) {
            int frame = fb + r;
            if (frame < NSLOT) sWh[frame * W_STRIDE + W_P + n] = (_Float16)acc[r];
          }
        }
      }
    }
  }
  __syncthreads();   // single barrier: pads + x + w all visible

  // ------- P2: gather convolution, 8-m-wide trips, reversed-x, x-prefetch -------
  // Same per-thread shape and summation order as R12 -> bit-identical output.
  {
    const int col = t & 31;
    const int pb  = t >> 5;
    const int e   = 64 + 10 * pb;
    const int qq  = (e >= 80) ? 1 : 0;
    const int D   = e - 80 * qq;                    // per half-wave uniform, even
    float acc[10];
#pragma unroll
    for (int i = 0; i < 10; ++i) acc[i] = 0.f;

#pragma unroll 1
    for (int g = 2; g >= -1; --g) {                 // source frame F - g
      const int dlt = D + 80 * g;                   // even
      int Ulo = (dlt - 128) >> 3; if (Ulo < 0) Ulo = 0;
      int Uhi = (dlt + 9) >> 3;   if (Uhi > 9) Uhi = 9;
      if (Ulo > Uhi) continue;
      const int slot = col + qq - g + 2;            // 0..34
      const _Float16* wr = &sWh[slot * W_STRIDE];
      const _Float16* xr = &sXh[XPAD + slot * X_STRIDE];
      int wb = W_P + dlt - 8 * Ulo - 4;             // even; running tap base

      // w-window: wEa[k] = (w[wb-4+2k], w[wb-4+2k+1]) even-aligned b32 loads,
      // wOa[k] = odd pair via alignbit. PAIR(K)=(wr[wb+K], wr[wb+K+1]),
      // K in [-3,13] used. All out-of-range taps land in zero pads.
      h2 wEa[10], wOa[9];
#pragma unroll
      for (int k2 = 0; k2 < 10; ++k2) wEa[k2] = *(const h2*)&wr[wb - 4 + 2 * k2];
#pragma unroll
      for (int k2 = 0; k2 < 9; ++k2) wOa[k2] = mid_h2(wEa[k2], wEa[k2 + 1]);

      // x 1-trip prefetch: reversed rows -> aligned b64s give descending pairs.
      const _Float16* xp = &xr[72 - 8 * Ulo];
      f16x4 p0 = *(const f16x4*)&xp[0];
      f16x4 p1 = *(const f16x4*)&xp[4];

#define PAIRX(K) (((K) & 1) ? wOa[(((K) - 1) >> 1) + 2] : wEa[(((K) >> 1) + 2)])
#pragma unroll 4
      for (int U = Ulo; U <= Uhi; ++U) {
        f16x4 q0 = p0, q1 = p1;                     // this trip's x
        xp -= 8;
        p0 = *(const f16x4*)&xp[0];                 // prefetch next trip
        p1 = *(const f16x4*)&xp[4];                 // (dead past Uhi; pad-safe)
        h2 xD; xD.x = q0.x; xD.y = q0.y;            // (x7,x6) — reg halves, free
        h2 xC; xC.x = q0.z; xC.y = q0.w;            // (x5,x4)
        h2 xB; xB.x = q1.x; xB.y = q1.y;            // (x3,x2)
        h2 xA; xA.x = q1.z; xA.y = q1.w;            // (x1,x0)
#pragma unroll
        for (int i = 0; i < 10; ++i) {
          float a = acc[i];
          a = __builtin_amdgcn_fdot2(xA, PAIRX(i + 3), a, false);  // m 8U+0,1
          a = __builtin_amdgcn_fdot2(xB, PAIRX(i + 1), a, false);  // m 8U+2,3
          a = __builtin_amdgcn_fdot2(xC, PAIRX(i - 1), a, false);  // m 8U+4,5
          a = __builtin_amdgcn_fdot2(xD, PAIRX(i - 3), a, false);  // m 8U+6,7
          acc[i] = a;
        }
        // slide window down 8 f16 = 4 pair-slots; W_P=24 => wb-12 >= 0 always
        const _Float16* wp = &wr[wb - 12];
#pragma unroll
        for (int k2 = 9; k2 >= 4; --k2) wEa[k2] = wEa[k2 - 4];
#pragma unroll
        for (int k2 = 8; k2 >= 4; --k2) wOa[k2] = wOa[k2 - 4];
        wEa[0] = *(const h2*)&wp[0];
        wEa[1] = *(const h2*)&wp[2];
        wEa[2] = *(const h2*)&wp[4];
        wEa[3] = *(const h2*)&wp[6];
        wOa[0] = mid_h2(wEa[0], wEa[1]);
        wOa[1] = mid_h2(wEa[1], wEa[2]);
        wOa[2] = mid_h2(wEa[2], wEa[3]);
        wOa[3] = mid_h2(wEa[3], wEa[4]);
        wb -= 8;
      }
#undef PAIRX
    }

    // exactly-once writeout: u0 = 80*col + 10*pb (even -> float2 stores)
    float* Ob = Og_ + (size_t)b * 320000 + 2560 * bx + 80 * col + 10 * pb;
#pragma unroll
    for (int s = 0; s < 5; ++s) {
      float2 v; v.x = acc[2 * s]; v.y = acc[2 * s + 1];
      *(float2*)&Ob[2 * s] = v;
    }
  }
}

extern "C" void kernel_launch(void* const* d_in, const int* in_sizes, int n_in,
                              void* d_out, int out_size, void* d_ws, size_t ws_size,
                              hipStream_t stream) {
  const float* H     = (const float*)d_in[0];   // [32,4000,65] fp32
  const float* noise = (const float*)d_in[1];   // [32,4000,80] fp32
  float* out = (float*)d_out;                   // [32,320000] fp32
  _Float16* M = (_Float16*)d_ws;                // 27,648 B of scratch
  (void)in_sizes; (void)n_in; (void)ws_size; (void)out_size;

  minit_kernel<<<54, 256, 0, stream>>>(M);      // rebuilt every call (ws re-poisoned)
  dim3 grid(125, 32, 1);
  fng_kernel<<<grid, NT, 0, stream>>>(H, noise, out, M);
}